// Round 11
// baseline (396.228 us; speedup 1.0000x reference)
//
#include <hip/hip_runtime.h>

typedef unsigned short u16;
typedef unsigned int u32;
typedef __attribute__((ext_vector_type(4))) float f32x4;
typedef __attribute__((ext_vector_type(8))) short short8;
typedef __attribute__((ext_vector_type(4))) unsigned int u32x4;

#define DEV __device__ __forceinline__

DEV float bf2f(u16 u){ union{u32 i; float f;} x; x.i = ((u32)u)<<16; return x.f; }
DEV u16 f2bf(float f){ union{u32 i; float f;} x; x.f = f; u32 r = x.i + 0x7fffu + ((x.i>>16)&1u); return (u16)(r>>16); }

union U8 { u16 u[8]; short8 s; };

// async global -> LDS, 16B per lane (dest must be wave-uniform base + lane*16; ours is tid*16)
DEV void gl16(const u16* g, u16* l){
  __builtin_amdgcn_global_load_lds(
      (const __attribute__((address_space(1))) u32*)g,
      (__attribute__((address_space(3))) u32*)l, 16, 0, 0);
}

// fast tanh/sigmoid via v_exp + v_rcp (err ~1e-6, dwarfed by bf16 input rounding)
DEV float fast_htanh(float v){           // 0.5*tanh(v)
  float vc = fminf(fmaxf(v, -15.f), 15.f);
  float e = __expf(2.f*vc);
  return 0.5f*(e - 1.f)*__builtin_amdgcn_rcpf(e + 1.f);
}
DEV float fast_sigmoid(float v){
  float e = __expf(-v);
  return __builtin_amdgcn_rcpf(1.f + e);
}

// =================== split x into hi/lo bf16 planes ===================
__global__ __launch_bounds__(256) void splitx_kernel(const float* __restrict__ x,
    u16* __restrict__ xh, u16* __restrict__ xl)
{
  size_t base = ((size_t)blockIdx.x*256 + threadIdx.x) * 8;   // 16384*1024/8 threads
  f32x4 a = *(const f32x4*)(x + base), b = *(const f32x4*)(x + base + 4);
  U8 h, l;
  #pragma unroll
  for (int e=0;e<4;e++){
    u16 hh = f2bf(a[e]); h.u[e]   = hh; l.u[e]   = f2bf(a[e] - bf2f(hh));
    u16 gg = f2bf(b[e]); h.u[4+e] = gg; l.u[4+e] = f2bf(b[e] - bf2f(gg));
  }
  *(short8*)(xh + base) = h.s;
  *(short8*)(xl + base) = l.s;
}

// =================== weight concat / transpose -> hi/lo bf16 planes ===================
__global__ __launch_bounds__(256) void concat_kernel(
    const float* __restrict__ Wskew, const float* __restrict__ Wk, const float* __restrict__ Wv,
    const float* __restrict__ Wq, const float* __restrict__ Wbeta, const float* __restrict__ Wo,
    u16* __restrict__ Wh, u16* __restrict__ Wl, u16* __restrict__ WoT)
{
  int idx = blockIdx.x*256 + threadIdx.x;
  if (idx < 896*1024){
    int n = idx >> 10, kk = idx & 1023;
    float v;
    if (n < 448)      v = Wskew[kk*448 + n];
    else if (n < 576) v = Wk[kk*128 + (n-448)];
    else if (n < 704) v = Wv[kk*128 + (n-576)];
    else if (n < 832) v = Wq[kk*128 + (n-704)];
    else if (n < 848) v = Wbeta[kk*16 + (n-832)];
    else              v = 0.f;
    u16 h = f2bf(v);
    Wh[idx] = h;
    Wl[idx] = f2bf(v - bf2f(h));
  } else {
    int r = idx - 896*1024;
    int n = r >> 7, kk = r & 127;
    WoT[r] = f2bf(Wo[kk*1024 + n]);
  }
}

// =================== proj GEMM: 4-plane global_load_lds, double-buffered ===================
__global__ __launch_bounds__(256) void gemm_proj_kernel(
    const u16* __restrict__ Ah, const u16* __restrict__ Al,
    const u16* __restrict__ Bh, const u16* __restrict__ Bl,
    float* __restrict__ C, const float* __restrict__ bias)
{
  __shared__ u16 L[2*4*4096];
  const int tid = threadIdx.x;
  const int wave = tid >> 6;
  const int lane = tid & 63;
  const int quad = lane >> 4, l15 = lane & 15;
  const int m0 = blockIdx.x * 128, n0 = blockIdx.y * 128;
  const bool full = (blockIdx.y < 4);
  const int wm = (wave >> 1) * 64, wn = (wave & 1) * 64;
  const bool wantLow = full && !(blockIdx.y == 3 && wn == 64);
  const bool skipBl1 = (blockIdx.y == 3);
  const int K = 1024, ldc = 896;
  const int sr = tid >> 2;
  const int sc = tid & 3;
  const int fS = (sr & 3) ^ ((sr >> 2) & 3);
  const int scS = ((sc ^ fS) << 3);
  const size_t gA0 = (size_t)(m0 + sr)*K + scS, gA1 = gA0 + (size_t)64*K;
  const size_t gB0 = (size_t)(n0 + sr)*K + scS, gB1 = gB0 + (size_t)64*K;
  const int d0 = tid*8, d1 = d0 + 2048;
  const int fR = (l15 & 3) ^ ((l15 >> 2) & 3);
  const int rq = ((quad ^ fR) << 3);

  auto STAGE = [&](int buf, int kb){
    u16* Lb = L + buf*16384;
    gl16(Ah + gA0 + kb, Lb + d0);
    gl16(Ah + gA1 + kb, Lb + d1);
    gl16(Bh + gB0 + kb, Lb + 4096 + d0);
    gl16(Bh + gB1 + kb, Lb + 4096 + d1);
    if (full){
      gl16(Al + gA0 + kb, Lb + 8192 + d0);
      gl16(Al + gA1 + kb, Lb + 8192 + d1);
      gl16(Bl + gB0 + kb, Lb + 12288 + d0);
      if (!skipBl1) gl16(Bl + gB1 + kb, Lb + 12288 + d1);
    }
  };

  f32x4 acc[4][4] = {};
  STAGE(0, 0);
  __syncthreads();
  int cur = 0;
  for (int kb = 0; kb < K; kb += 32){
    if (kb + 32 < K) STAGE(cur^1, kb + 32);
    u16* Lb = L + cur*16384;
    short8 afh[4], bfh[4];
    #pragma unroll
    for (int mi=0;mi<4;mi++) afh[mi] = *(const short8*)&Lb[(wm + mi*16 + l15)*32 + rq];
    #pragma unroll
    for (int ni=0;ni<4;ni++) bfh[ni] = *(const short8*)&Lb[4096 + (wn + ni*16 + l15)*32 + rq];
    #pragma unroll
    for (int mi=0;mi<4;mi++)
      #pragma unroll
      for (int ni=0;ni<4;ni++)
        acc[mi][ni] = __builtin_amdgcn_mfma_f32_16x16x32_bf16(afh[mi], bfh[ni], acc[mi][ni], 0,0,0);
    if (wantLow){
      short8 afl[4], bfl[4];
      #pragma unroll
      for (int mi=0;mi<4;mi++) afl[mi] = *(const short8*)&Lb[8192 + (wm + mi*16 + l15)*32 + rq];
      #pragma unroll
      for (int ni=0;ni<4;ni++) bfl[ni] = *(const short8*)&Lb[12288 + (wn + ni*16 + l15)*32 + rq];
      #pragma unroll
      for (int mi=0;mi<4;mi++)
        #pragma unroll
        for (int ni=0;ni<4;ni++){
          acc[mi][ni] = __builtin_amdgcn_mfma_f32_16x16x32_bf16(afh[mi], bfl[ni], acc[mi][ni], 0,0,0);
          acc[mi][ni] = __builtin_amdgcn_mfma_f32_16x16x32_bf16(afl[mi], bfh[ni], acc[mi][ni], 0,0,0);
        }
    }
    __syncthreads();
    cur ^= 1;
  }
  #pragma unroll
  for (int mi=0;mi<4;mi++){
    #pragma unroll
    for (int ni=0;ni<4;ni++){
      const int col = n0 + wn + ni*16 + l15;
      const int rb_ = m0 + wm + mi*16 + quad*4;
      #pragma unroll
      for (int r=0;r<4;r++){
        float v = acc[mi][ni][r];
        const int row = rb_ + r;
        if (col < 448) v = fast_htanh(v);
        else if (col >= 832 && col < 848) v = fast_sigmoid(v + bias[col-832]);
        C[(size_t)row*ldc + col] = v;
      }
    }
  }
}

// =================== output GEMM: bf16 A/Bt -> fp32 C (dbuf pipeline, K=128) ===================
__global__ __launch_bounds__(256) void gemm_out_kernel(
    const u16* __restrict__ A, const u16* __restrict__ Bt, float* __restrict__ C)
{
  __shared__ u16 L[2*2*4096];
  const int tid = threadIdx.x;
  const int wave = tid >> 6;
  const int lane = tid & 63;
  const int quad = lane >> 4, l15 = lane & 15;
  const int m0 = blockIdx.x * 128, n0 = blockIdx.y * 128;
  const int wm = (wave >> 1) * 64, wn = (wave & 1) * 64;
  const int K = 128, ldc = 1024;
  const int sr = tid >> 2;
  const int sc = tid & 3;
  const int fS = (sr & 3) ^ ((sr >> 2) & 3);
  const int scS = ((sc ^ fS) << 3);
  const size_t gA0 = (size_t)(m0 + sr)*K + scS, gA1 = gA0 + (size_t)64*K;
  const size_t gB0 = (size_t)(n0 + sr)*K + scS, gB1 = gB0 + (size_t)64*K;
  const int d0 = tid*8, d1 = d0 + 2048;
  const int fR = (l15 & 3) ^ ((l15 >> 2) & 3);
  const int rq = ((quad ^ fR) << 3);

  auto STAGE = [&](int buf, int kb){
    u16* Lb = L + buf*8192;
    gl16(A  + gA0 + kb, Lb + d0);
    gl16(A  + gA1 + kb, Lb + d1);
    gl16(Bt + gB0 + kb, Lb + 4096 + d0);
    gl16(Bt + gB1 + kb, Lb + 4096 + d1);
  };

  f32x4 acc[4][4] = {};
  STAGE(0, 0);
  __syncthreads();
  int cur = 0;
  for (int kb = 0; kb < K; kb += 32){
    if (kb + 32 < K) STAGE(cur^1, kb + 32);
    u16* Lb = L + cur*8192;
    short8 af[4], bf8[4];
    #pragma unroll
    for (int mi=0;mi<4;mi++) af[mi] = *(const short8*)&Lb[(wm + mi*16 + l15)*32 + rq];
    #pragma unroll
    for (int ni=0;ni<4;ni++) bf8[ni] = *(const short8*)&Lb[4096 + (wn + ni*16 + l15)*32 + rq];
    #pragma unroll
    for (int mi=0;mi<4;mi++)
      #pragma unroll
      for (int ni=0;ni<4;ni++)
        acc[mi][ni] = __builtin_amdgcn_mfma_f32_16x16x32_bf16(af[mi], bf8[ni], acc[mi][ni], 0,0,0);
    __syncthreads();
    cur ^= 1;
  }
  #pragma unroll
  for (int mi=0;mi<4;mi++)
    #pragma unroll
    for (int ni=0;ni<4;ni++){
      const int col = n0 + wn + ni*16 + l15;
      const int rb_ = m0 + wm + mi*16 + quad*4;
      #pragma unroll
      for (int r=0;r<4;r++)
        C[(size_t)(rb_ + r)*ldc + col] = acc[mi][ni][r];
    }
}

// =================== fused expm + chunk prefix scan (1 thread = 1 matrix) ===================
// Regalloc control (R4-R10 forensics): __launch_bounds__ min-waves alone is NOT enough — the
// allocator's own occupancy heuristic picked 5 waves/EU in some builds (96 VGPR -> 14MB spill,
// 129us: R5/R9). waves_per_eu(1,2) fixed the spill (R10) but capped occupancy at 2 waves/EU
// -> latency-bound at ~67us. waves_per_eu(3,4) pins the sweet spot: VGPR cap = 512/3 ~ 168
// (peak live set ~146 floats fits: scan M[64]+Q[64]+r[8]; squaring M+T=128; Horner is the
// commuted in-place form M <- (M·B)*coef + I, row-local, no T buffer) AND >=3 waves/SIMD
// (12/CU) for latency hiding — the configuration the R6 lucky-build reached (~40us).
__device__ constexpr int TRI_I[28] = {0,0,0,0,0,0,0, 1,1,1,1,1,1, 2,2,2,2,2, 3,3,3,3, 4,4,4, 5,5, 6};
__device__ constexpr int TRI_J[28] = {1,2,3,4,5,6,7, 2,3,4,5,6,7, 3,4,5,6,7, 4,5,6,7, 5,6,7, 6,7, 7};

__global__ __launch_bounds__(64) __attribute__((amdgpu_waves_per_eu(3, 4)))
void expm_scan_kernel(const float* __restrict__ proj, float* __restrict__ OR)
{
  __shared__ float S0[16*64*4];   // [j(0..15)][t(0..63)] f32x4
  const int t = threadIdx.x;
  const int s = blockIdx.x >> 6, c = blockIdx.x & 63;   // 4096 blocks
  const int b = s >> 4, h = s & 15;
  const int row = b*4096 + c*64 + t;
  const float* sk = proj + (size_t)row*896 + h*28;

  float v[28];
  {
    f32x4 vv[7];
    #pragma unroll
    for (int i=0;i<7;i++) vv[i] = *(const f32x4*)(sk + 4*i);
    #pragma unroll
    for (int i=0;i<28;i++) v[i] = vv[i>>2][i&3] * 0.0625f;
  }

  float M[64], T[64];
  // init M = B/6 + I
  #pragma unroll
  for (int i=0;i<8;i++){
    #pragma unroll
    for (int jj=0;jj<8;jj++){
      float bv = 0.f;
      if (i < jj){ const int k = i*7 - (i*(i-1))/2 + jj - i - 1; bv =  v[k]; }
      if (i > jj){ const int k = jj*7 - (jj*(jj-1))/2 + i - jj - 1; bv = -v[k]; }
      M[i*8+jj] = bv*(1.f/6.f) + ((i==jj)?1.f:0.f);
    }
  }
  // Horner: M <- (M·B)*coef + I, row-local in-place (no T buffer needed)
  const float coef[5] = {0.2f, 0.25f, 1.f/3.f, 0.5f, 1.f};
  #pragma unroll
  for (int st=0; st<5; st++){
    #pragma unroll
    for (int i=0;i<8;i++){
      float rowv[8];
      #pragma unroll
      for (int a=0;a<8;a++) rowv[a] = M[i*8+a];
      #pragma unroll
      for (int cc=0;cc<8;cc++){
        float acc = 0.f;
        #pragma unroll
        for (int a=0;a<8;a++){
          if (a == cc) continue;
          const int k = (a<cc) ? (a*7 - (a*(a-1))/2 + cc - a - 1)
                               : (cc*7 - (cc*(cc-1))/2 + a - cc - 1);
          if (a<cc) acc = fmaf( rowv[a], v[k], acc);
          else      acc = fmaf(-rowv[a], v[k], acc);
        }
        M[i*8+cc] = acc*coef[st] + ((i==cc)?1.f:0.f);
      }
    }
  }
  // 4 squarings (reg-reg; fits the 168-VGPR budget)
  #pragma unroll
  for (int sq=0; sq<4; sq++){
    #pragma unroll
    for (int i=0;i<8;i++)
      #pragma unroll
      for (int cc=0;cc<8;cc++){
        float acc = 0.f;
        #pragma unroll
        for (int a=0;a<8;a++) acc = fmaf(M[i*8+a], M[a*8+cc], acc);
        T[i*8+cc] = acc;
      }
    #pragma unroll
    for (int f=0;f<64;f++) M[f] = T[f];
  }
  #pragma unroll
  for (int j=0;j<16;j++){
    f32x4 w = {M[4*j], M[4*j+1], M[4*j+2], M[4*j+3]};
    *(f32x4*)&S0[(j*64 + t)*4] = w;
  }
  __syncthreads();

  #pragma unroll
  for (int d=0; d<6; d++){
    const int off = 1 << d;
    if (t >= off){
      float Q[64];
      #pragma unroll
      for (int j=0;j<16;j++){
        f32x4 x = *(const f32x4*)&S0[(j*64 + (t-off))*4];
        Q[4*j]=x[0]; Q[4*j+1]=x[1]; Q[4*j+2]=x[2]; Q[4*j+3]=x[3];
      }
      #pragma unroll
      for (int i=0;i<8;i++){
        float r[8];
        #pragma unroll
        for (int cc=0;cc<8;cc++){
          float acc = 0.f;
          #pragma unroll
          for (int a=0;a<8;a++) acc = fmaf(M[i*8+a], Q[a*8+cc], acc);
          r[cc] = acc;
        }
        #pragma unroll
        for (int cc=0;cc<8;cc++) M[i*8+cc] = r[cc];
      }
    }
    if (d < 5){
      #pragma unroll
      for (int j=0;j<16;j++){
        f32x4 w = {M[4*j], M[4*j+1], M[4*j+2], M[4*j+3]};
        *(f32x4*)&S0[(j*64 + t)*4] = w;
      }
      __syncthreads();
    }
  }

  float* dst = OR + ((size_t)s*4096 + (size_t)c*64 + t)*64;
  #pragma unroll
  for (int j=0;j<16;j++){
    const int rb = 4*(j&1), col = j>>1;
    f32x4 w = {M[(rb+0)*8 + col], M[(rb+1)*8 + col], M[(rb+2)*8 + col], M[(rb+3)*8 + col]};
    *(f32x4*)(dst + 4*j) = w;
  }
}

// helpers: 8x8 matvec with 16 f32x4 regs
DEV void load16(const float* p, f32x4* M){
  #pragma unroll
  for (int q=0;q<16;q++) M[q] = *(const f32x4*)(p + 4*q);
}
DEV void rm_matvec8(const f32x4* M16, const float* x, float* res){
  #pragma unroll
  for (int i=0;i<8;i++){
    float acc = 0.f;
    #pragma unroll
    for (int a=0;a<8;a++) acc = fmaf(M16[2*i + (a>>2)][a&3], x[a], acc);
    res[i] = acc;
  }
}
DEV void cm_matvec8(const f32x4* M16, const float* x, float* res){
  #pragma unroll
  for (int i=0;i<8;i++){
    float acc = 0.f;
    #pragma unroll
    for (int a=0;a<8;a++) acc = fmaf(M16[2*a + (i>>2)][i&3], x[a], acc);
    res[i] = acc;
  }
}

// =================== C2: parallel Hillis-Steele scan of chunk products -> Rbase_c ===================
// keep (1,2): live set here is M+Q+R = 192+ floats — a 168-VGPR cap would spill.
__global__ __launch_bounds__(64) __attribute__((amdgpu_waves_per_eu(1, 2)))
void chunkscan_kernel(const float* __restrict__ OR, float* __restrict__ Rbase)
{
  __shared__ float S[64*68];
  const int t = threadIdx.x;
  const int s = blockIdx.x;
  float M[64];
  const float* qs = OR + ((size_t)s*4096 + (size_t)t*64 + 63)*64;   // Q_t (chunk-final P)
  #pragma unroll
  for (int j=0;j<16;j++){
    f32x4 x = *(const f32x4*)(qs + 4*j);
    M[4*j]=x[0]; M[4*j+1]=x[1]; M[4*j+2]=x[2]; M[4*j+3]=x[3];
  }
  #pragma unroll
  for (int j=0;j<16;j++){
    f32x4 w = {M[4*j],M[4*j+1],M[4*j+2],M[4*j+3]};
    *(f32x4*)&S[t*68 + 4*j] = w;
  }
  __syncthreads();
  #pragma unroll
  for (int d=0; d<6; d++){
    const int off = 1 << d;
    if (t >= off){
      float Q[64];
      const float* p = &S[(t-off)*68];
      #pragma unroll
      for (int j=0;j<16;j++){
        f32x4 x = *(const f32x4*)(p + 4*j);
        Q[4*j]=x[0]; Q[4*j+1]=x[1]; Q[4*j+2]=x[2]; Q[4*j+3]=x[3];
      }
      float R[64];
      #pragma unroll
      for (int cc=0;cc<8;cc++)
        #pragma unroll
        for (int i=0;i<8;i++){
          float acc = 0.f;
          #pragma unroll
          for (int a=0;a<8;a++) acc = fmaf(M[a*8+i], Q[cc*8+a], acc);
          R[cc*8+i] = acc;
        }
      #pragma unroll
      for (int f=0;f<64;f++) M[f] = R[f];
    }
    if (d < 5){
      #pragma unroll
      for (int j=0;j<16;j++){
        f32x4 w = {M[4*j],M[4*j+1],M[4*j+2],M[4*j+3]};
        *(f32x4*)&S[t*68 + 4*j] = w;
      }
      __syncthreads();
    }
  }
  if (t < 63){
    float* dst = Rbase + ((size_t)s*64 + t + 1)*64;
    #pragma unroll
    for (int j=0;j<16;j++){
      f32x4 w = {M[4*j],M[4*j+1],M[4*j+2],M[4*j+3]};
      *(f32x4*)(dst + 4*j) = w;
    }
  }
  if (t == 0){
    float* dst = Rbase + (size_t)s*64*64;
    #pragma unroll
    for (int cc=0;cc<8;cc++)
      #pragma unroll
      for (int i=0;i<8;i++) dst[cc*8+i] = (i==cc) ? 1.f : 0.f;
  }
}

// =================== C3: rotate k/v/q via R_t^T = Rbase^T (P^T .) ===================
__global__ __launch_bounds__(256) void rotate_kvq_kernel(const float* __restrict__ OR, const float* __restrict__ Rbase,
    float* __restrict__ proj)
{
  int tid = blockIdx.x*256 + threadIdx.x;   // 262144
  int s = tid >> 12, t = tid & 4095;
  int c = t >> 6;
  int b = s >> 4, h = s & 15;
  int row = b*4096 + t;
  const float* slot = OR + ((size_t)s*4096 + t)*64;
  float* pr = proj + (size_t)row*896;
  float k[8], v[8], q[8];
  { f32x4 a = *(const f32x4*)(pr+448+h*8), b2 = *(const f32x4*)(pr+452+h*8);
    #pragma unroll
    for (int i=0;i<4;i++){ k[i]=a[i]; k[4+i]=b2[i]; } }
  { f32x4 a = *(const f32x4*)(pr+576+h*8), b2 = *(const f32x4*)(pr+580+h*8);
    #pragma unroll
    for (int i=0;i<4;i++){ v[i]=a[i]; v[4+i]=b2[i]; } }
  { f32x4 a = *(const f32x4*)(pr+704+h*8), b2 = *(const f32x4*)(pr+708+h*8);
    #pragma unroll
    for (int i=0;i<4;i++){ q[i]=a[i]; q[4+i]=b2[i]; } }
  float nn = 0.f;
  #pragma unroll
  for (int i=0;i<8;i++) nn = fmaf(k[i],k[i],nn);
  float inv = 1.f / fmaxf(sqrtf(nn), 1e-6f);
  #pragma unroll
  for (int i=0;i<8;i++) k[i] *= inv;

  f32x4 M[16];
  load16(slot, M);                           // P col-major -> rm gives P^T x
  float uk[8], uv[8], uq[8];
  rm_matvec8(M, k, uk);
  rm_matvec8(M, v, uv);
  rm_matvec8(M, q, uq);
  load16(Rbase + ((size_t)s*64 + c)*64, M);  // Rbase col-major -> rm gives Rbase^T x
  float kt[8], vt[8], qt[8];
  rm_matvec8(M, uk, kt);
  rm_matvec8(M, uv, vt);
  rm_matvec8(M, uq, qt);

  float beta = pr[832+h];
  float qk = 0.f;
  #pragma unroll
  for (int j=0;j<8;j++) qk = fmaf(kt[j], qt[j], qk);
  float* sip = pr + h*28;     // dead skew slot of this (row,h); writes <448, reads >=448
  f32x4 w0={kt[0],kt[1],kt[2],kt[3]}, w1={kt[4],kt[5],kt[6],kt[7]};
  f32x4 w2={vt[0],vt[1],vt[2],vt[3]}, w3={vt[4],vt[5],vt[6],vt[7]};
  f32x4 w4={qt[0],qt[1],qt[2],qt[3]}, w5={qt[4],qt[5],qt[6],qt[7]};
  f32x4 w6={beta, qk, 0.f, 0.f};
  *(f32x4*)(sip)=w0; *(f32x4*)(sip+4)=w1; *(f32x4*)(sip+8)=w2; *(f32x4*)(sip+12)=w3;
  *(f32x4*)(sip+16)=w4; *(f32x4*)(sip+20)=w5; *(f32x4*)(sip+24)=w6;
}

// =================== D: chunk-parallel delta scan (256 chunks x 16 steps) ===================
__global__ __launch_bounds__(256) void scan_pass1_kernel(const float* __restrict__ proj,
    float* __restrict__ Mbuf, float* __restrict__ wbuf)
{
  int tid = blockIdx.x*256 + threadIdx.x;   // 131072 = 16384 tasks * 8 lanes
  int task = tid >> 3, j = tid & 7;         // task = s*256 + c
  int s = task >> 8, c = task & 255;
  int b = s >> 4, h = s & 15;
  const float* rec = proj + ((size_t)b*4096 + (size_t)c*16)*896 + h*28;
  float m[8], w[8];
  #pragma unroll
  for (int i=0;i<8;i++){ m[i] = (i==j)?1.f:0.f; w[i] = 0.f; }
  f32x4 k0 = *(const f32x4*)(rec), k1 = *(const f32x4*)(rec+4);
  float vt = rec[8+j];
  float beta = rec[24];
  for (int tt=0; tt<16; tt++){
    const float* pn = rec + (size_t)(tt+1)*896;   // prefetch (last iter value unused)
    f32x4 nk0 = *(const f32x4*)(pn), nk1 = *(const f32x4*)(pn+4);
    float nvt = pn[8+j];
    float nbeta = pn[24];
    float s1, s2;
    s1 = ((k0[0]*m[0] + k0[1]*m[1]) + (k0[2]*m[2] + k0[3]*m[3]))
       + ((k1[0]*m[4] + k1[1]*m[5]) + (k1[2]*m[6] + k1[3]*m[7]));
    s2 = ((k0[0]*w[0] + k0[1]*w[1]) + (k0[2]*w[2] + k0[3]*w[3]))
       + ((k1[0]*w[4] + k1[1]*w[5]) + (k1[2]*w[6] + k1[3]*w[7]));
    float c1 = -beta*s1, c2 = beta*(vt - s2);
    #pragma unroll
    for (int i=0;i<4;i++){ m[i] = fmaf(k0[i], c1, m[i]); m[4+i] = fmaf(k1[i], c1, m[4+i]); }
    #pragma unroll
    for (int i=0;i<4;i++){ w[i] = fmaf(k0[i], c2, w[i]); w[4+i] = fmaf(k1[i], c2, w[4+i]); }
    k0=nk0; k1=nk1; vt=nvt; beta=nbeta;
  }
  float* md = Mbuf + (size_t)task*64 + j*8;
  float* wd = wbuf + (size_t)task*64 + j*8;
  f32x4 m0={m[0],m[1],m[2],m[3]}, m1={m[4],m[5],m[6],m[7]};
  f32x4 w0={w[0],w[1],w[2],w[3]}, w1={w[4],w[5],w[6],w[7]};
  *(f32x4*)(md) = m0; *(f32x4*)(md+4) = m1;
  *(f32x4*)(wd) = w0; *(f32x4*)(wd+4) = w1;
}

// =================== scan_mid: parallel affine scan over 256 chunks ===================
__global__ __launch_bounds__(512) void scan_mid_kernel(const float* __restrict__ Mbuf,
    const float* __restrict__ wbuf, float* __restrict__ dstart)
{
  __shared__ float SM[256*68];
  __shared__ float SW[256*68];
  const int tid = threadIdx.x;
  const int c = tid >> 1, g = tid & 1;
  const int s = blockIdx.x;
  const size_t base = (size_t)s*256*64;
  const float* mp = Mbuf + base + (size_t)c*64 + 32*g;
  const float* wp = wbuf + base + (size_t)c*64 + 32*g;
  float W[32];
  {
    float* sm = &SM[c*68 + 32*g];
    float* sw = &SW[c*68 + 32*g];
    #pragma unroll
    for (int j=0;j<8;j++){
      f32x4 a = *(const f32x4*)(mp + 4*j);
      f32x4 b = *(const f32x4*)(wp + 4*j);
      *(f32x4*)(sm + 4*j) = a;
      *(f32x4*)(sw + 4*j) = b;
      W[4*j]=b[0]; W[4*j+1]=b[1]; W[4*j+2]=b[2]; W[4*j+3]=b[3];
    }
  }
  __syncthreads();
  for (int d=0; d<8; d++){
    const int off = 1 << d;
    const bool act = (c >= off);
    float Mo[64], pM[32], pW[32];
    if (act){
      const float* om = &SM[c*68];
      #pragma unroll
      for (int j=0;j<16;j++){
        f32x4 x = *(const f32x4*)(om + 4*j);
        Mo[4*j]=x[0]; Mo[4*j+1]=x[1]; Mo[4*j+2]=x[2]; Mo[4*j+3]=x[3];
      }
      const float* qm = &SM[(c-off)*68 + 32*g];
      const float* qw = &SW[(c-off)*68 + 32*g];
      #pragma unroll
      for (int j=0;j<8;j++){
        f32x4 x = *(const f32x4*)(qm + 4*j);
        f32x4 y = *(const f32x4*)(qw + 4*j);
        pM[4*j]=x[0]; pM[4*j+1]=x[1]; pM[4*j+2]=x[2]; pM[4*j+3]=x[3];
        pW[4*j]=y[0]; pW[4*j+1]=y[1]; pW[4*j+2]=y[2]; pW[4*j+3]=y[3];
      }
    }
    __syncthreads();
    if (act){
      float nM[32], nW[32];
      #pragma unroll
      for (int cl=0; cl<4; cl++){
        #pragma unroll
        for (int i=0;i<8;i++){
          float aM = 0.f, aW = 0.f;
          #pragma unroll
          for (int a=0;a<8;a++){
            aM = fmaf(Mo[a*8+i], pM[cl*8+a], aM);
            aW = fmaf(Mo[a*8+i], pW[cl*8+a], aW);
          }
          nM[cl*8+i] = aM;
          nW[cl*8+i] = aW + W[cl*8+i];
        }
      }
      float* sm = &SM[c*68 + 32*g];
      float* sw = &SW[c*68 + 32*g];
      #pragma unroll
      for (int j=0;j<8;j++){
        f32x4 x = {nM[4*j], nM[4*j+1], nM[4*j+2], nM[4*j+3]};
        f32x4 y = {nW[4*j], nW[4*j+1], nW[4*j+2], nW[4*j+3]};
        *(f32x4*)(sm + 4*j) = x;
        *(f32x4*)(sw + 4*j) = y;
      }
      #pragma unroll
      for (int f=0;f<32;f++) W[f] = nW[f];
    }
    __syncthreads();
  }
  if (c < 255){
    float* dd = dstart + base + (size_t)(c+1)*64 + 32*g;
    #pragma unroll
    for (int j=0;j<8;j++){
      f32x4 y = {W[4*j],W[4*j+1],W[4*j+2],W[4*j+3]};
      *(f32x4*)(dd + 4*j) = y;
    }
  }
  if (c == 0){
    float* dd = dstart + base + 32*g;
    f32x4 z = {0.f,0.f,0.f,0.f};
    #pragma unroll
    for (int j=0;j<8;j++) *(f32x4*)(dd + 4*j) = z;
  }
}

__global__ __launch_bounds__(256) void scan_pass2_kernel(const float* __restrict__ proj,
    const float* __restrict__ dstart, float* __restrict__ oo)
{
  int tid = blockIdx.x*256 + threadIdx.x;   // 131072
  int task = tid >> 3, j = tid & 7;
  int s = task >> 8, c = task & 255;
  int b = s >> 4, h = s & 15;
  const float* rec = proj + ((size_t)b*4096 + (size_t)c*16)*896 + h*28;
  float* op = oo + (((size_t)s*4096 + (size_t)c*16)*8) + j;
  float d[8];
  { const float* ds = dstart + (size_t)task*64 + j*8;
    f32x4 a = *(const f32x4*)(ds), b2 = *(const f32x4*)(ds+4);
    #pragma unroll
    for (int i=0;i<4;i++){ d[i]=a[i]; d[4+i]=b2[i]; } }
  f32x4 k0 = *(const f32x4*)(rec),    k1 = *(const f32x4*)(rec+4);
  f32x4 q0 = *(const f32x4*)(rec+16), q1 = *(const f32x4*)(rec+20);
  f32x4 mb = *(const f32x4*)(rec+24);
  float vt = rec[8+j];
  for (int tt=0; tt<16; tt++){
    const float* pn = rec + (size_t)(tt+1)*896;   // prefetch
    f32x4 nk0 = *(const f32x4*)(pn),    nk1 = *(const f32x4*)(pn+4);
    f32x4 nq0 = *(const f32x4*)(pn+16), nq1 = *(const f32x4*)(pn+20);
    f32x4 nmb = *(const f32x4*)(pn+24);
    float nvt = pn[8+j];
    float kd, qd;
    kd = ((k0[0]*d[0] + k0[1]*d[1]) + (k0[2]*d[2] + k0[3]*d[3]))
       + ((k1[0]*d[4] + k1[1]*d[5]) + (k1[2]*d[6] + k1[3]*d[7]));
    qd = ((q0[0]*d[0] + q0[1]*d[1]) + (q0[2]*d[2] + q0[3]*d[3]))
       + ((q1[0]*d[4] + q1[1]*d[5]) + (q1[2]*d[6] + q1[3]*d[7]));
    float w_ = mb[0] * (vt - kd);
    #pragma unroll
    for (int i=0;i<4;i++){ d[i] = fmaf(k0[i], w_, d[i]); d[4+i] = fmaf(k1[i], w_, d[4+i]); }
    op[(size_t)tt*8] = fmaf(mb[1], w_, qd);
    k0=nk0; k1=nk1; q0=nq0; q1=nq1; mb=nmb; vt=nvt;
  }
}

// =================== E: rotate outputs back: o = P (Rbase o~), write bf16 ===================
__global__ __launch_bounds__(256) void rotout_kernel(const float* __restrict__ OR, const float* __restrict__ Rbase,
                                                     const float* __restrict__ oo, u16* __restrict__ obf)
{
  int tid = blockIdx.x*256 + threadIdx.x;   // 262144
  int s = tid >> 12, t = tid & 4095;
  int c = t >> 6;
  int b = s >> 4, h = s & 15;
  int row = b*4096 + t;
  float u[8];
  { const float* up = oo + ((size_t)s*4096 + t)*8;
    f32x4 a = *(const f32x4*)(up), b2 = *(const f32x4*)(up+4);
    #pragma unroll
    for (int i=0;i<4;i++){ u[i]=a[i]; u[4+i]=b2[i]; } }
  f32x4 M[16];
  load16(Rbase + ((size_t)s*64 + c)*64, M);  // col-major -> cm gives Rbase * u
  float w[8];
  cm_matvec8(M, u, w);
  load16(OR + ((size_t)s*4096 + t)*64, M);   // P col-major -> cm gives P * w
  float o[8];
  cm_matvec8(M, w, o);
  u32 p0 = (u32)f2bf(o[0]) | ((u32)f2bf(o[1])<<16);
  u32 p1 = (u32)f2bf(o[2]) | ((u32)f2bf(o[3])<<16);
  u32 p2 = (u32)f2bf(o[4]) | ((u32)f2bf(o[5])<<16);
  u32 p3 = (u32)f2bf(o[6]) | ((u32)f2bf(o[7])<<16);
  u32x4 pk = {p0,p1,p2,p3};
  *(u32x4*)(void*)(obf + (size_t)row*128 + h*8) = pk;
}

// =================== launch ===================
extern "C" void kernel_launch(void* const* d_in, const int* in_sizes, int n_in,
                              void* d_out, int out_size, void* d_ws, size_t ws_size,
                              hipStream_t stream)
{
  const float* x     = (const float*)d_in[0];
  const float* Wskew = (const float*)d_in[1];
  const float* Wk    = (const float*)d_in[2];
  const float* Wv    = (const float*)d_in[3];
  const float* Wq    = (const float*)d_in[4];
  const float* Wbeta = (const float*)d_in[5];
  const float* bbeta = (const float*)d_in[6];
  const float* Wo    = (const float*)d_in[7];

  char* w = (char*)d_ws; size_t off = 0;
  auto alloc = [&](size_t bytes)->void*{ void* p = w + off; off += (bytes + 255) & ~(size_t)255; return p; };
  u16*   Wh     = (u16*)  alloc((size_t)896*1024*2);
  u16*   Wl     = (u16*)  alloc((size_t)896*1024*2);
  u16*   WoT    = (u16*)  alloc((size_t)1024*128*2);
  float* proj   = (float*)alloc((size_t)16384*896*4);
  float* OR     = (float*)alloc((size_t)262144*64*4);
  float* Rbase  = (float*)alloc((size_t)64*64*64*4);
  float* oo     = (float*)alloc((size_t)262144*8*4);
  float* Mbuf   = (float*)alloc((size_t)16384*64*4);
  float* wbuf   = (float*)alloc((size_t)16384*64*4);
  float* dstart = (float*)alloc((size_t)16384*64*4);
  // aliases: xh/xl live only until gemm_proj; OR is written first by expm_scan (after)
  u16*   xh     = (u16*)OR;                       // 32 MB
  u16*   xl     = xh + (size_t)16384*1024;        // 32 MB  (OR region is 64 MB)
  u16*   obf    = (u16*)proj;   // proj fully dead after scan pass2

  hipLaunchKernelGGL(splitx_kernel, dim3(8192), dim3(256), 0, stream, x, xh, xl);
  hipLaunchKernelGGL(concat_kernel, dim3(4096), dim3(256), 0, stream,
                     Wskew, Wk, Wv, Wq, Wbeta, Wo, Wh, Wl, WoT);
  hipLaunchKernelGGL(gemm_proj_kernel, dim3(128,7), dim3(256), 0, stream,
                     xh, xl, Wh, Wl, proj, bbeta);
  hipLaunchKernelGGL(expm_scan_kernel, dim3(4096), dim3(64), 0, stream, proj, OR);
  hipLaunchKernelGGL(chunkscan_kernel, dim3(64), dim3(64), 0, stream, OR, Rbase);
  hipLaunchKernelGGL(rotate_kvq_kernel, dim3(1024), dim3(256), 0, stream, OR, Rbase, proj);
  hipLaunchKernelGGL(scan_pass1_kernel, dim3(512), dim3(256), 0, stream, proj, Mbuf, wbuf);
  hipLaunchKernelGGL(scan_mid_kernel, dim3(64), dim3(512), 0, stream, Mbuf, wbuf, dstart);
  hipLaunchKernelGGL(scan_pass2_kernel, dim3(512), dim3(256), 0, stream, proj, dstart, oo);
  hipLaunchKernelGGL(rotout_kernel, dim3(1024), dim3(256), 0, stream, OR, Rbase, oo, obf);
  hipLaunchKernelGGL(gemm_out_kernel, dim3(128,8), dim3(256), 0, stream,
                     obf, WoT, (float*)d_out);
}

// Round 12
// 360.242 us; speedup vs baseline: 1.0999x; 1.0999x over previous
//
#include <hip/hip_runtime.h>

typedef unsigned short u16;
typedef unsigned int u32;
typedef __attribute__((ext_vector_type(4))) float f32x4;
typedef __attribute__((ext_vector_type(8))) short short8;
typedef __attribute__((ext_vector_type(4))) unsigned int u32x4;

#define DEV __device__ __forceinline__

DEV float bf2f(u16 u){ union{u32 i; float f;} x; x.i = ((u32)u)<<16; return x.f; }
DEV u16 f2bf(float f){ union{u32 i; float f;} x; x.f = f; u32 r = x.i + 0x7fffu + ((x.i>>16)&1u); return (u16)(r>>16); }

union U8 { u16 u[8]; short8 s; };

// async global -> LDS, 16B per lane (dest must be wave-uniform base + lane*16; ours is tid*16)
DEV void gl16(const u16* g, u16* l){
  __builtin_amdgcn_global_load_lds(
      (const __attribute__((address_space(1))) u32*)g,
      (__attribute__((address_space(3))) u32*)l, 16, 0, 0);
}

// fast tanh/sigmoid via v_exp + v_rcp (err ~1e-6, dwarfed by bf16 input rounding)
DEV float fast_htanh(float v){           // 0.5*tanh(v)
  float vc = fminf(fmaxf(v, -15.f), 15.f);
  float e = __expf(2.f*vc);
  return 0.5f*(e - 1.f)*__builtin_amdgcn_rcpf(e + 1.f);
}
DEV float fast_sigmoid(float v){
  float e = __expf(-v);
  return __builtin_amdgcn_rcpf(1.f + e);
}

// =================== split x into hi/lo bf16 planes ===================
__global__ __launch_bounds__(256) void splitx_kernel(const float* __restrict__ x,
    u16* __restrict__ xh, u16* __restrict__ xl)
{
  size_t base = ((size_t)blockIdx.x*256 + threadIdx.x) * 8;   // 16384*1024/8 threads
  f32x4 a = *(const f32x4*)(x + base), b = *(const f32x4*)(x + base + 4);
  U8 h, l;
  #pragma unroll
  for (int e=0;e<4;e++){
    u16 hh = f2bf(a[e]); h.u[e]   = hh; l.u[e]   = f2bf(a[e] - bf2f(hh));
    u16 gg = f2bf(b[e]); h.u[4+e] = gg; l.u[4+e] = f2bf(b[e] - bf2f(gg));
  }
  *(short8*)(xh + base) = h.s;
  *(short8*)(xl + base) = l.s;
}

// =================== weight concat / transpose -> hi/lo bf16 planes ===================
__global__ __launch_bounds__(256) void concat_kernel(
    const float* __restrict__ Wskew, const float* __restrict__ Wk, const float* __restrict__ Wv,
    const float* __restrict__ Wq, const float* __restrict__ Wbeta, const float* __restrict__ Wo,
    u16* __restrict__ Wh, u16* __restrict__ Wl, u16* __restrict__ WoT)
{
  int idx = blockIdx.x*256 + threadIdx.x;
  if (idx < 896*1024){
    int n = idx >> 10, kk = idx & 1023;
    float v;
    if (n < 448)      v = Wskew[kk*448 + n];
    else if (n < 576) v = Wk[kk*128 + (n-448)];
    else if (n < 704) v = Wv[kk*128 + (n-576)];
    else if (n < 832) v = Wq[kk*128 + (n-704)];
    else if (n < 848) v = Wbeta[kk*16 + (n-832)];
    else              v = 0.f;
    u16 h = f2bf(v);
    Wh[idx] = h;
    Wl[idx] = f2bf(v - bf2f(h));
  } else {
    int r = idx - 896*1024;
    int n = r >> 7, kk = r & 127;
    WoT[r] = f2bf(Wo[kk*1024 + n]);
  }
}

// =================== proj GEMM: 4-plane global_load_lds, double-buffered ===================
__global__ __launch_bounds__(256) void gemm_proj_kernel(
    const u16* __restrict__ Ah, const u16* __restrict__ Al,
    const u16* __restrict__ Bh, const u16* __restrict__ Bl,
    float* __restrict__ C, const float* __restrict__ bias)
{
  __shared__ u16 L[2*4*4096];
  const int tid = threadIdx.x;
  const int wave = tid >> 6;
  const int lane = tid & 63;
  const int quad = lane >> 4, l15 = lane & 15;
  const int m0 = blockIdx.x * 128, n0 = blockIdx.y * 128;
  const bool full = (blockIdx.y < 4);
  const int wm = (wave >> 1) * 64, wn = (wave & 1) * 64;
  const bool wantLow = full && !(blockIdx.y == 3 && wn == 64);
  const bool skipBl1 = (blockIdx.y == 3);
  const int K = 1024, ldc = 896;
  const int sr = tid >> 2;
  const int sc = tid & 3;
  const int fS = (sr & 3) ^ ((sr >> 2) & 3);
  const int scS = ((sc ^ fS) << 3);
  const size_t gA0 = (size_t)(m0 + sr)*K + scS, gA1 = gA0 + (size_t)64*K;
  const size_t gB0 = (size_t)(n0 + sr)*K + scS, gB1 = gB0 + (size_t)64*K;
  const int d0 = tid*8, d1 = d0 + 2048;
  const int fR = (l15 & 3) ^ ((l15 >> 2) & 3);
  const int rq = ((quad ^ fR) << 3);

  auto STAGE = [&](int buf, int kb){
    u16* Lb = L + buf*16384;
    gl16(Ah + gA0 + kb, Lb + d0);
    gl16(Ah + gA1 + kb, Lb + d1);
    gl16(Bh + gB0 + kb, Lb + 4096 + d0);
    gl16(Bh + gB1 + kb, Lb + 4096 + d1);
    if (full){
      gl16(Al + gA0 + kb, Lb + 8192 + d0);
      gl16(Al + gA1 + kb, Lb + 8192 + d1);
      gl16(Bl + gB0 + kb, Lb + 12288 + d0);
      if (!skipBl1) gl16(Bl + gB1 + kb, Lb + 12288 + d1);
    }
  };

  f32x4 acc[4][4] = {};
  STAGE(0, 0);
  __syncthreads();
  int cur = 0;
  for (int kb = 0; kb < K; kb += 32){
    if (kb + 32 < K) STAGE(cur^1, kb + 32);
    u16* Lb = L + cur*16384;
    short8 afh[4], bfh[4];
    #pragma unroll
    for (int mi=0;mi<4;mi++) afh[mi] = *(const short8*)&Lb[(wm + mi*16 + l15)*32 + rq];
    #pragma unroll
    for (int ni=0;ni<4;ni++) bfh[ni] = *(const short8*)&Lb[4096 + (wn + ni*16 + l15)*32 + rq];
    #pragma unroll
    for (int mi=0;mi<4;mi++)
      #pragma unroll
      for (int ni=0;ni<4;ni++)
        acc[mi][ni] = __builtin_amdgcn_mfma_f32_16x16x32_bf16(afh[mi], bfh[ni], acc[mi][ni], 0,0,0);
    if (wantLow){
      short8 afl[4], bfl[4];
      #pragma unroll
      for (int mi=0;mi<4;mi++) afl[mi] = *(const short8*)&Lb[8192 + (wm + mi*16 + l15)*32 + rq];
      #pragma unroll
      for (int ni=0;ni<4;ni++) bfl[ni] = *(const short8*)&Lb[12288 + (wn + ni*16 + l15)*32 + rq];
      #pragma unroll
      for (int mi=0;mi<4;mi++)
        #pragma unroll
        for (int ni=0;ni<4;ni++){
          acc[mi][ni] = __builtin_amdgcn_mfma_f32_16x16x32_bf16(afh[mi], bfl[ni], acc[mi][ni], 0,0,0);
          acc[mi][ni] = __builtin_amdgcn_mfma_f32_16x16x32_bf16(afl[mi], bfh[ni], acc[mi][ni], 0,0,0);
        }
    }
    __syncthreads();
    cur ^= 1;
  }
  #pragma unroll
  for (int mi=0;mi<4;mi++){
    #pragma unroll
    for (int ni=0;ni<4;ni++){
      const int col = n0 + wn + ni*16 + l15;
      const int rb_ = m0 + wm + mi*16 + quad*4;
      #pragma unroll
      for (int r=0;r<4;r++){
        float v = acc[mi][ni][r];
        const int row = rb_ + r;
        if (col < 448) v = fast_htanh(v);
        else if (col >= 832 && col < 848) v = fast_sigmoid(v + bias[col-832]);
        C[(size_t)row*ldc + col] = v;
      }
    }
  }
}

// =================== output GEMM: bf16 A/Bt -> fp32 C (dbuf pipeline, K=128) ===================
__global__ __launch_bounds__(256) void gemm_out_kernel(
    const u16* __restrict__ A, const u16* __restrict__ Bt, float* __restrict__ C)
{
  __shared__ u16 L[2*2*4096];
  const int tid = threadIdx.x;
  const int wave = tid >> 6;
  const int lane = tid & 63;
  const int quad = lane >> 4, l15 = lane & 15;
  const int m0 = blockIdx.x * 128, n0 = blockIdx.y * 128;
  const int wm = (wave >> 1) * 64, wn = (wave & 1) * 64;
  const int K = 128, ldc = 1024;
  const int sr = tid >> 2;
  const int sc = tid & 3;
  const int fS = (sr & 3) ^ ((sr >> 2) & 3);
  const int scS = ((sc ^ fS) << 3);
  const size_t gA0 = (size_t)(m0 + sr)*K + scS, gA1 = gA0 + (size_t)64*K;
  const size_t gB0 = (size_t)(n0 + sr)*K + scS, gB1 = gB0 + (size_t)64*K;
  const int d0 = tid*8, d1 = d0 + 2048;
  const int fR = (l15 & 3) ^ ((l15 >> 2) & 3);
  const int rq = ((quad ^ fR) << 3);

  auto STAGE = [&](int buf, int kb){
    u16* Lb = L + buf*8192;
    gl16(A  + gA0 + kb, Lb + d0);
    gl16(A  + gA1 + kb, Lb + d1);
    gl16(Bt + gB0 + kb, Lb + 4096 + d0);
    gl16(Bt + gB1 + kb, Lb + 4096 + d1);
  };

  f32x4 acc[4][4] = {};
  STAGE(0, 0);
  __syncthreads();
  int cur = 0;
  for (int kb = 0; kb < K; kb += 32){
    if (kb + 32 < K) STAGE(cur^1, kb + 32);
    u16* Lb = L + cur*8192;
    short8 af[4], bf8[4];
    #pragma unroll
    for (int mi=0;mi<4;mi++) af[mi] = *(const short8*)&Lb[(wm + mi*16 + l15)*32 + rq];
    #pragma unroll
    for (int ni=0;ni<4;ni++) bf8[ni] = *(const short8*)&Lb[4096 + (wn + ni*16 + l15)*32 + rq];
    #pragma unroll
    for (int mi=0;mi<4;mi++)
      #pragma unroll
      for (int ni=0;ni<4;ni++)
        acc[mi][ni] = __builtin_amdgcn_mfma_f32_16x16x32_bf16(af[mi], bf8[ni], acc[mi][ni], 0,0,0);
    __syncthreads();
    cur ^= 1;
  }
  #pragma unroll
  for (int mi=0;mi<4;mi++)
    #pragma unroll
    for (int ni=0;ni<4;ni++){
      const int col = n0 + wn + ni*16 + l15;
      const int rb_ = m0 + wm + mi*16 + quad*4;
      #pragma unroll
      for (int r=0;r<4;r++)
        C[(size_t)(rb_ + r)*ldc + col] = acc[mi][ni][r];
    }
}

// =================== fused expm + chunk prefix scan (1 thread = 1 matrix) ===================
// Regalloc (R4-R11 forensics): the only load-bearing knob is waves_per_eu MAX=2 — with it the
// allocator budgets ~256 VGPR and the ~136-float live set never spills (R10). min bounds and
// max>=3 are ignored by the heuristic (R11: (3,4) -> 84 VGPR, 55MB spill, 90us). Keep (1,2).
// Output: P in BF16 (ORbf, col-major) — P entries are in [-1,1]; bf16 is applied only ONCE per
// vector downstream (err ~1e-3 relative). The COMPOUNDING path (chunkscan's 64-product) gets
// the chunk-final P in fp32 via Pfin (1MB).
__device__ constexpr int TRI_I[28] = {0,0,0,0,0,0,0, 1,1,1,1,1,1, 2,2,2,2,2, 3,3,3,3, 4,4,4, 5,5, 6};
__device__ constexpr int TRI_J[28] = {1,2,3,4,5,6,7, 2,3,4,5,6,7, 3,4,5,6,7, 4,5,6,7, 5,6,7, 6,7, 7};

__global__ __launch_bounds__(64) __attribute__((amdgpu_waves_per_eu(1, 2)))
void expm_scan_kernel(const float* __restrict__ proj, u16* __restrict__ ORbf, float* __restrict__ Pfin)
{
  __shared__ float S0[16*64*4];   // [j(0..15)][t(0..63)] f32x4
  const int t = threadIdx.x;
  const int s = blockIdx.x >> 6, c = blockIdx.x & 63;   // 4096 blocks
  const int b = s >> 4, h = s & 15;
  const int row = b*4096 + c*64 + t;
  const float* sk = proj + (size_t)row*896 + h*28;

  float v[28];
  {
    f32x4 vv[7];
    #pragma unroll
    for (int i=0;i<7;i++) vv[i] = *(const f32x4*)(sk + 4*i);
    #pragma unroll
    for (int i=0;i<28;i++) v[i] = vv[i>>2][i&3] * 0.0625f;
  }

  float M[64], T[64];
  // init M = B/6 + I
  #pragma unroll
  for (int i=0;i<8;i++){
    #pragma unroll
    for (int jj=0;jj<8;jj++){
      float bv = 0.f;
      if (i < jj){ const int k = i*7 - (i*(i-1))/2 + jj - i - 1; bv =  v[k]; }
      if (i > jj){ const int k = jj*7 - (jj*(jj-1))/2 + i - jj - 1; bv = -v[k]; }
      M[i*8+jj] = bv*(1.f/6.f) + ((i==jj)?1.f:0.f);
    }
  }
  // Horner: M <- (M·B)*coef + I, row-local in-place (B commutes with polynomials in B)
  const float coef[5] = {0.2f, 0.25f, 1.f/3.f, 0.5f, 1.f};
  #pragma unroll
  for (int st=0; st<5; st++){
    #pragma unroll
    for (int i=0;i<8;i++){
      float rowv[8];
      #pragma unroll
      for (int a=0;a<8;a++) rowv[a] = M[i*8+a];
      #pragma unroll
      for (int cc=0;cc<8;cc++){
        float acc = 0.f;
        #pragma unroll
        for (int a=0;a<8;a++){
          if (a == cc) continue;
          const int k = (a<cc) ? (a*7 - (a*(a-1))/2 + cc - a - 1)
                               : (cc*7 - (cc*(cc-1))/2 + a - cc - 1);
          if (a<cc) acc = fmaf( rowv[a], v[k], acc);
          else      acc = fmaf(-rowv[a], v[k], acc);
        }
        M[i*8+cc] = acc*coef[st] + ((i==cc)?1.f:0.f);
      }
    }
  }
  // 4 squarings
  #pragma unroll
  for (int sq=0; sq<4; sq++){
    #pragma unroll
    for (int i=0;i<8;i++)
      #pragma unroll
      for (int cc=0;cc<8;cc++){
        float acc = 0.f;
        #pragma unroll
        for (int a=0;a<8;a++) acc = fmaf(M[i*8+a], M[a*8+cc], acc);
        T[i*8+cc] = acc;
      }
    #pragma unroll
    for (int f=0;f<64;f++) M[f] = T[f];
  }
  #pragma unroll
  for (int j=0;j<16;j++){
    f32x4 w = {M[4*j], M[4*j+1], M[4*j+2], M[4*j+3]};
    *(f32x4*)&S0[(j*64 + t)*4] = w;
  }
  __syncthreads();

  #pragma unroll
  for (int d=0; d<6; d++){
    const int off = 1 << d;
    if (t >= off){
      float Q[64];
      #pragma unroll
      for (int j=0;j<16;j++){
        f32x4 x = *(const f32x4*)&S0[(j*64 + (t-off))*4];
        Q[4*j]=x[0]; Q[4*j+1]=x[1]; Q[4*j+2]=x[2]; Q[4*j+3]=x[3];
      }
      #pragma unroll
      for (int i=0;i<8;i++){
        float r[8];
        #pragma unroll
        for (int cc=0;cc<8;cc++){
          float acc = 0.f;
          #pragma unroll
          for (int a=0;a<8;a++) acc = fmaf(M[i*8+a], Q[a*8+cc], acc);
          r[cc] = acc;
        }
        #pragma unroll
        for (int cc=0;cc<8;cc++) M[i*8+cc] = r[cc];
      }
    }
    if (d < 5){
      #pragma unroll
      for (int j=0;j<16;j++){
        f32x4 w = {M[4*j], M[4*j+1], M[4*j+2], M[4*j+3]};
        *(f32x4*)&S0[(j*64 + t)*4] = w;
      }
      __syncthreads();
    }
  }

  // ---- write P col-major bf16: ORbf[slot + a*8 + i] = bf16(M[i][a]); 8x 16B stores
  u16* dst = ORbf + ((size_t)s*4096 + (size_t)c*64 + t)*64;
  #pragma unroll
  for (int g=0; g<8; g++){
    u32 p0 = (u32)f2bf(M[0*8+g]) | ((u32)f2bf(M[1*8+g])<<16);
    u32 p1 = (u32)f2bf(M[2*8+g]) | ((u32)f2bf(M[3*8+g])<<16);
    u32 p2 = (u32)f2bf(M[4*8+g]) | ((u32)f2bf(M[5*8+g])<<16);
    u32 p3 = (u32)f2bf(M[6*8+g]) | ((u32)f2bf(M[7*8+g])<<16);
    u32x4 pk = {p0,p1,p2,p3};
    *(u32x4*)(void*)(dst + g*8) = pk;
  }
  // ---- chunk-final P in fp32 for the compounding path (chunkscan)
  if (t == 63){
    float* pf = Pfin + ((size_t)s*64 + c)*64;
    #pragma unroll
    for (int a=0;a<8;a++){
      f32x4 w  = {M[0*8+a], M[1*8+a], M[2*8+a], M[3*8+a]};
      f32x4 w2 = {M[4*8+a], M[5*8+a], M[6*8+a], M[7*8+a]};
      *(f32x4*)(pf + a*8)     = w;
      *(f32x4*)(pf + a*8 + 4) = w2;
    }
  }
}

// helpers: 8x8 matvec with 16 f32x4 regs
DEV void load16(const float* p, f32x4* M){
  #pragma unroll
  for (int q=0;q<16;q++) M[q] = *(const f32x4*)(p + 4*q);
}
// unpack a 64-element bf16 slot (flat order preserved) into 16 f32x4
DEV void load16bf(const u16* p, f32x4* M){
  #pragma unroll
  for (int q=0;q<8;q++){
    u32x4 x = *(const u32x4*)(const void*)(p + q*8);
    f32x4 a = { bf2f((u16)x[0]), bf2f((u16)(x[0]>>16)), bf2f((u16)x[1]), bf2f((u16)(x[1]>>16)) };
    f32x4 b = { bf2f((u16)x[2]), bf2f((u16)(x[2]>>16)), bf2f((u16)x[3]), bf2f((u16)(x[3]>>16)) };
    M[2*q] = a; M[2*q+1] = b;
  }
}
DEV void rm_matvec8(const f32x4* M16, const float* x, float* res){
  #pragma unroll
  for (int i=0;i<8;i++){
    float acc = 0.f;
    #pragma unroll
    for (int a=0;a<8;a++) acc = fmaf(M16[2*i + (a>>2)][a&3], x[a], acc);
    res[i] = acc;
  }
}
DEV void cm_matvec8(const f32x4* M16, const float* x, float* res){
  #pragma unroll
  for (int i=0;i<8;i++){
    float acc = 0.f;
    #pragma unroll
    for (int a=0;a<8;a++) acc = fmaf(M16[2*a + (i>>2)][i&3], x[a], acc);
    res[i] = acc;
  }
}

// =================== C2: parallel Hillis-Steele scan of chunk products -> Rbase_c ===================
// reads fp32 Pfin (compounding path stays full precision). keep (1,2): live set M+Q+R ~ 192.
__global__ __launch_bounds__(64) __attribute__((amdgpu_waves_per_eu(1, 2)))
void chunkscan_kernel(const float* __restrict__ Pfin, float* __restrict__ Rbase)
{
  __shared__ float S[64*68];
  const int t = threadIdx.x;
  const int s = blockIdx.x;
  float M[64];
  const float* qs = Pfin + ((size_t)s*64 + t)*64;   // Q_t (chunk-final P, fp32)
  #pragma unroll
  for (int j=0;j<16;j++){
    f32x4 x = *(const f32x4*)(qs + 4*j);
    M[4*j]=x[0]; M[4*j+1]=x[1]; M[4*j+2]=x[2]; M[4*j+3]=x[3];
  }
  #pragma unroll
  for (int j=0;j<16;j++){
    f32x4 w = {M[4*j],M[4*j+1],M[4*j+2],M[4*j+3]};
    *(f32x4*)&S[t*68 + 4*j] = w;
  }
  __syncthreads();
  #pragma unroll
  for (int d=0; d<6; d++){
    const int off = 1 << d;
    if (t >= off){
      float Q[64];
      const float* p = &S[(t-off)*68];
      #pragma unroll
      for (int j=0;j<16;j++){
        f32x4 x = *(const f32x4*)(p + 4*j);
        Q[4*j]=x[0]; Q[4*j+1]=x[1]; Q[4*j+2]=x[2]; Q[4*j+3]=x[3];
      }
      float R[64];
      #pragma unroll
      for (int cc=0;cc<8;cc++)
        #pragma unroll
        for (int i=0;i<8;i++){
          float acc = 0.f;
          #pragma unroll
          for (int a=0;a<8;a++) acc = fmaf(M[a*8+i], Q[cc*8+a], acc);
          R[cc*8+i] = acc;
        }
      #pragma unroll
      for (int f=0;f<64;f++) M[f] = R[f];
    }
    if (d < 5){
      #pragma unroll
      for (int j=0;j<16;j++){
        f32x4 w = {M[4*j],M[4*j+1],M[4*j+2],M[4*j+3]};
        *(f32x4*)&S[t*68 + 4*j] = w;
      }
      __syncthreads();
    }
  }
  if (t < 63){
    float* dst = Rbase + ((size_t)s*64 + t + 1)*64;
    #pragma unroll
    for (int j=0;j<16;j++){
      f32x4 w = {M[4*j],M[4*j+1],M[4*j+2],M[4*j+3]};
      *(f32x4*)(dst + 4*j) = w;
    }
  }
  if (t == 0){
    float* dst = Rbase + (size_t)s*64*64;
    #pragma unroll
    for (int cc=0;cc<8;cc++)
      #pragma unroll
      for (int i=0;i<8;i++) dst[cc*8+i] = (i==cc) ? 1.f : 0.f;
  }
}

// =================== C3: rotate k/v/q via R_t^T = Rbase^T (P^T .) — P from bf16 ===================
__global__ __launch_bounds__(256) void rotate_kvq_kernel(const u16* __restrict__ ORbf, const float* __restrict__ Rbase,
    float* __restrict__ proj)
{
  int tid = blockIdx.x*256 + threadIdx.x;   // 262144
  int s = tid >> 12, t = tid & 4095;
  int c = t >> 6;
  int b = s >> 4, h = s & 15;
  int row = b*4096 + t;
  const u16* slot = ORbf + ((size_t)s*4096 + t)*64;
  float* pr = proj + (size_t)row*896;
  float k[8], v[8], q[8];
  { f32x4 a = *(const f32x4*)(pr+448+h*8), b2 = *(const f32x4*)(pr+452+h*8);
    #pragma unroll
    for (int i=0;i<4;i++){ k[i]=a[i]; k[4+i]=b2[i]; } }
  { f32x4 a = *(const f32x4*)(pr+576+h*8), b2 = *(const f32x4*)(pr+580+h*8);
    #pragma unroll
    for (int i=0;i<4;i++){ v[i]=a[i]; v[4+i]=b2[i]; } }
  { f32x4 a = *(const f32x4*)(pr+704+h*8), b2 = *(const f32x4*)(pr+708+h*8);
    #pragma unroll
    for (int i=0;i<4;i++){ q[i]=a[i]; q[4+i]=b2[i]; } }
  float nn = 0.f;
  #pragma unroll
  for (int i=0;i<8;i++) nn = fmaf(k[i],k[i],nn);
  float inv = 1.f / fmaxf(sqrtf(nn), 1e-6f);
  #pragma unroll
  for (int i=0;i<8;i++) k[i] *= inv;

  f32x4 M[16];
  load16bf(slot, M);                         // P col-major -> rm gives P^T x
  float uk[8], uv[8], uq[8];
  rm_matvec8(M, k, uk);
  rm_matvec8(M, v, uv);
  rm_matvec8(M, q, uq);
  load16(Rbase + ((size_t)s*64 + c)*64, M);  // Rbase col-major -> rm gives Rbase^T x
  float kt[8], vt[8], qt[8];
  rm_matvec8(M, uk, kt);
  rm_matvec8(M, uv, vt);
  rm_matvec8(M, uq, qt);

  float beta = pr[832+h];
  float qk = 0.f;
  #pragma unroll
  for (int j=0;j<8;j++) qk = fmaf(kt[j], qt[j], qk);
  float* sip = pr + h*28;     // dead skew slot of this (row,h); writes <448, reads >=448
  f32x4 w0={kt[0],kt[1],kt[2],kt[3]}, w1={kt[4],kt[5],kt[6],kt[7]};
  f32x4 w2={vt[0],vt[1],vt[2],vt[3]}, w3={vt[4],vt[5],vt[6],vt[7]};
  f32x4 w4={qt[0],qt[1],qt[2],qt[3]}, w5={qt[4],qt[5],qt[6],qt[7]};
  f32x4 w6={beta, qk, 0.f, 0.f};
  *(f32x4*)(sip)=w0; *(f32x4*)(sip+4)=w1; *(f32x4*)(sip+8)=w2; *(f32x4*)(sip+12)=w3;
  *(f32x4*)(sip+16)=w4; *(f32x4*)(sip+20)=w5; *(f32x4*)(sip+24)=w6;
}

// =================== D: chunk-parallel delta scan (256 chunks x 16 steps) ===================
__global__ __launch_bounds__(256) void scan_pass1_kernel(const float* __restrict__ proj,
    float* __restrict__ Mbuf, float* __restrict__ wbuf)
{
  int tid = blockIdx.x*256 + threadIdx.x;   // 131072 = 16384 tasks * 8 lanes
  int task = tid >> 3, j = tid & 7;         // task = s*256 + c
  int s = task >> 8, c = task & 255;
  int b = s >> 4, h = s & 15;
  const float* rec = proj + ((size_t)b*4096 + (size_t)c*16)*896 + h*28;
  float m[8], w[8];
  #pragma unroll
  for (int i=0;i<8;i++){ m[i] = (i==j)?1.f:0.f; w[i] = 0.f; }
  f32x4 k0 = *(const f32x4*)(rec), k1 = *(const f32x4*)(rec+4);
  float vt = rec[8+j];
  float beta = rec[24];
  for (int tt=0; tt<16; tt++){
    const float* pn = rec + (size_t)(tt+1)*896;   // prefetch (last iter value unused)
    f32x4 nk0 = *(const f32x4*)(pn), nk1 = *(const f32x4*)(pn+4);
    float nvt = pn[8+j];
    float nbeta = pn[24];
    float s1, s2;
    s1 = ((k0[0]*m[0] + k0[1]*m[1]) + (k0[2]*m[2] + k0[3]*m[3]))
       + ((k1[0]*m[4] + k1[1]*m[5]) + (k1[2]*m[6] + k1[3]*m[7]));
    s2 = ((k0[0]*w[0] + k0[1]*w[1]) + (k0[2]*w[2] + k0[3]*w[3]))
       + ((k1[0]*w[4] + k1[1]*w[5]) + (k1[2]*w[6] + k1[3]*w[7]));
    float c1 = -beta*s1, c2 = beta*(vt - s2);
    #pragma unroll
    for (int i=0;i<4;i++){ m[i] = fmaf(k0[i], c1, m[i]); m[4+i] = fmaf(k1[i], c1, m[4+i]); }
    #pragma unroll
    for (int i=0;i<4;i++){ w[i] = fmaf(k0[i], c2, w[i]); w[4+i] = fmaf(k1[i], c2, w[4+i]); }
    k0=nk0; k1=nk1; vt=nvt; beta=nbeta;
  }
  float* md = Mbuf + (size_t)task*64 + j*8;
  float* wd = wbuf + (size_t)task*64 + j*8;
  f32x4 m0={m[0],m[1],m[2],m[3]}, m1={m[4],m[5],m[6],m[7]};
  f32x4 w0={w[0],w[1],w[2],w[3]}, w1={w[4],w[5],w[6],w[7]};
  *(f32x4*)(md) = m0; *(f32x4*)(md+4) = m1;
  *(f32x4*)(wd) = w0; *(f32x4*)(wd+4) = w1;
}

// =================== scan_mid: parallel affine scan over 256 chunks ===================
__global__ __launch_bounds__(512) void scan_mid_kernel(const float* __restrict__ Mbuf,
    const float* __restrict__ wbuf, float* __restrict__ dstart)
{
  __shared__ float SM[256*68];
  __shared__ float SW[256*68];
  const int tid = threadIdx.x;
  const int c = tid >> 1, g = tid & 1;
  const int s = blockIdx.x;
  const size_t base = (size_t)s*256*64;
  const float* mp = Mbuf + base + (size_t)c*64 + 32*g;
  const float* wp = wbuf + base + (size_t)c*64 + 32*g;
  float W[32];
  {
    float* sm = &SM[c*68 + 32*g];
    float* sw = &SW[c*68 + 32*g];
    #pragma unroll
    for (int j=0;j<8;j++){
      f32x4 a = *(const f32x4*)(mp + 4*j);
      f32x4 b = *(const f32x4*)(wp + 4*j);
      *(f32x4*)(sm + 4*j) = a;
      *(f32x4*)(sw + 4*j) = b;
      W[4*j]=b[0]; W[4*j+1]=b[1]; W[4*j+2]=b[2]; W[4*j+3]=b[3];
    }
  }
  __syncthreads();
  for (int d=0; d<8; d++){
    const int off = 1 << d;
    const bool act = (c >= off);
    float Mo[64], pM[32], pW[32];
    if (act){
      const float* om = &SM[c*68];
      #pragma unroll
      for (int j=0;j<16;j++){
        f32x4 x = *(const f32x4*)(om + 4*j);
        Mo[4*j]=x[0]; Mo[4*j+1]=x[1]; Mo[4*j+2]=x[2]; Mo[4*j+3]=x[3];
      }
      const float* qm = &SM[(c-off)*68 + 32*g];
      const float* qw = &SW[(c-off)*68 + 32*g];
      #pragma unroll
      for (int j=0;j<8;j++){
        f32x4 x = *(const f32x4*)(qm + 4*j);
        f32x4 y = *(const f32x4*)(qw + 4*j);
        pM[4*j]=x[0]; pM[4*j+1]=x[1]; pM[4*j+2]=x[2]; pM[4*j+3]=x[3];
        pW[4*j]=y[0]; pW[4*j+1]=y[1]; pW[4*j+2]=y[2]; pW[4*j+3]=y[3];
      }
    }
    __syncthreads();
    if (act){
      float nM[32], nW[32];
      #pragma unroll
      for (int cl=0; cl<4; cl++){
        #pragma unroll
        for (int i=0;i<8;i++){
          float aM = 0.f, aW = 0.f;
          #pragma unroll
          for (int a=0;a<8;a++){
            aM = fmaf(Mo[a*8+i], pM[cl*8+a], aM);
            aW = fmaf(Mo[a*8+i], pW[cl*8+a], aW);
          }
          nM[cl*8+i] = aM;
          nW[cl*8+i] = aW + W[cl*8+i];
        }
      }
      float* sm = &SM[c*68 + 32*g];
      float* sw = &SW[c*68 + 32*g];
      #pragma unroll
      for (int j=0;j<8;j++){
        f32x4 x = {nM[4*j], nM[4*j+1], nM[4*j+2], nM[4*j+3]};
        f32x4 y = {nW[4*j], nW[4*j+1], nW[4*j+2], nW[4*j+3]};
        *(f32x4*)(sm + 4*j) = x;
        *(f32x4*)(sw + 4*j) = y;
      }
      #pragma unroll
      for (int f=0;f<32;f++) W[f] = nW[f];
    }
    __syncthreads();
  }
  if (c < 255){
    float* dd = dstart + base + (size_t)(c+1)*64 + 32*g;
    #pragma unroll
    for (int j=0;j<8;j++){
      f32x4 y = {W[4*j],W[4*j+1],W[4*j+2],W[4*j+3]};
      *(f32x4*)(dd + 4*j) = y;
    }
  }
  if (c == 0){
    float* dd = dstart + base + 32*g;
    f32x4 z = {0.f,0.f,0.f,0.f};
    #pragma unroll
    for (int j=0;j<8;j++) *(f32x4*)(dd + 4*j) = z;
  }
}

__global__ __launch_bounds__(256) void scan_pass2_kernel(const float* __restrict__ proj,
    const float* __restrict__ dstart, float* __restrict__ oo)
{
  int tid = blockIdx.x*256 + threadIdx.x;   // 131072
  int task = tid >> 3, j = tid & 7;
  int s = task >> 8, c = task & 255;
  int b = s >> 4, h = s & 15;
  const float* rec = proj + ((size_t)b*4096 + (size_t)c*16)*896 + h*28;
  float* op = oo + (((size_t)s*4096 + (size_t)c*16)*8) + j;
  float d[8];
  { const float* ds = dstart + (size_t)task*64 + j*8;
    f32x4 a = *(const f32x4*)(ds), b2 = *(const f32x4*)(ds+4);
    #pragma unroll
    for (int i=0;i<4;i++){ d[i]=a[i]; d[4+i]=b2[i]; } }
  f32x4 k0 = *(const f32x4*)(rec),    k1 = *(const f32x4*)(rec+4);
  f32x4 q0 = *(const f32x4*)(rec+16), q1 = *(const f32x4*)(rec+20);
  f32x4 mb = *(const f32x4*)(rec+24);
  float vt = rec[8+j];
  for (int tt=0; tt<16; tt++){
    const float* pn = rec + (size_t)(tt+1)*896;   // prefetch
    f32x4 nk0 = *(const f32x4*)(pn),    nk1 = *(const f32x4*)(pn+4);
    f32x4 nq0 = *(const f32x4*)(pn+16), nq1 = *(const f32x4*)(pn+20);
    f32x4 nmb = *(const f32x4*)(pn+24);
    float nvt = pn[8+j];
    float kd, qd;
    kd = ((k0[0]*d[0] + k0[1]*d[1]) + (k0[2]*d[2] + k0[3]*d[3]))
       + ((k1[0]*d[4] + k1[1]*d[5]) + (k1[2]*d[6] + k1[3]*d[7]));
    qd = ((q0[0]*d[0] + q0[1]*d[1]) + (q0[2]*d[2] + q0[3]*d[3]))
       + ((q1[0]*d[4] + q1[1]*d[5]) + (q1[2]*d[6] + q1[3]*d[7]));
    float w_ = mb[0] * (vt - kd);
    #pragma unroll
    for (int i=0;i<4;i++){ d[i] = fmaf(k0[i], w_, d[i]); d[4+i] = fmaf(k1[i], w_, d[4+i]); }
    op[(size_t)tt*8] = fmaf(mb[1], w_, qd);
    k0=nk0; k1=nk1; q0=nq0; q1=nq1; mb=nmb; vt=nvt;
  }
}

// =================== E: rotate outputs back: o = P (Rbase o~), P from bf16 ===================
__global__ __launch_bounds__(256) void rotout_kernel(const u16* __restrict__ ORbf, const float* __restrict__ Rbase,
                                                     const float* __restrict__ oo, u16* __restrict__ obf)
{
  int tid = blockIdx.x*256 + threadIdx.x;   // 262144
  int s = tid >> 12, t = tid & 4095;
  int c = t >> 6;
  int b = s >> 4, h = s & 15;
  int row = b*4096 + t;
  float u[8];
  { const float* up = oo + ((size_t)s*4096 + t)*8;
    f32x4 a = *(const f32x4*)(up), b2 = *(const f32x4*)(up+4);
    #pragma unroll
    for (int i=0;i<4;i++){ u[i]=a[i]; u[4+i]=b2[i]; } }
  f32x4 M[16];
  load16(Rbase + ((size_t)s*64 + c)*64, M);       // col-major -> cm gives Rbase * u
  float w[8];
  cm_matvec8(M, u, w);
  load16bf(ORbf + ((size_t)s*4096 + t)*64, M);    // P col-major (bf16) -> cm gives P * w
  float o[8];
  cm_matvec8(M, w, o);
  u32 p0 = (u32)f2bf(o[0]) | ((u32)f2bf(o[1])<<16);
  u32 p1 = (u32)f2bf(o[2]) | ((u32)f2bf(o[3])<<16);
  u32 p2 = (u32)f2bf(o[4]) | ((u32)f2bf(o[5])<<16);
  u32 p3 = (u32)f2bf(o[6]) | ((u32)f2bf(o[7])<<16);
  u32x4 pk = {p0,p1,p2,p3};
  *(u32x4*)(void*)(obf + (size_t)row*128 + h*8) = pk;
}

// =================== launch ===================
extern "C" void kernel_launch(void* const* d_in, const int* in_sizes, int n_in,
                              void* d_out, int out_size, void* d_ws, size_t ws_size,
                              hipStream_t stream)
{
  const float* x     = (const float*)d_in[0];
  const float* Wskew = (const float*)d_in[1];
  const float* Wk    = (const float*)d_in[2];
  const float* Wv    = (const float*)d_in[3];
  const float* Wq    = (const float*)d_in[4];
  const float* Wbeta = (const float*)d_in[5];
  const float* bbeta = (const float*)d_in[6];
  const float* Wo    = (const float*)d_in[7];

  char* w = (char*)d_ws; size_t off = 0;
  auto alloc = [&](size_t bytes)->void*{ void* p = w + off; off += (bytes + 255) & ~(size_t)255; return p; };
  u16*   Wh     = (u16*)  alloc((size_t)896*1024*2);
  u16*   Wl     = (u16*)  alloc((size_t)896*1024*2);
  u16*   WoT    = (u16*)  alloc((size_t)1024*128*2);
  float* proj   = (float*)alloc((size_t)16384*896*4);
  char*  ORal   = (char*) alloc((size_t)64*1024*1024);  // 64MB region: ORbf uses first 32MB
  float* Pfin   = (float*)alloc((size_t)4096*64*4);     // 1MB: chunk-final P fp32
  float* Rbase  = (float*)alloc((size_t)64*64*64*4);
  float* oo     = (float*)alloc((size_t)262144*8*4);
  float* Mbuf   = (float*)alloc((size_t)16384*64*4);
  float* wbuf   = (float*)alloc((size_t)16384*64*4);
  float* dstart = (float*)alloc((size_t)16384*64*4);
  // aliases: xh/xl live only until gemm_proj; ORbf is written first by expm_scan (after)
  u16*   ORbf   = (u16*)ORal;                     // 32 MB
  u16*   xh     = (u16*)ORal;                     // 32 MB
  u16*   xl     = xh + (size_t)16384*1024;        // 32 MB (second half of the 64MB region)
  u16*   obf    = (u16*)proj;   // proj fully dead after scan pass2

  hipLaunchKernelGGL(splitx_kernel, dim3(8192), dim3(256), 0, stream, x, xh, xl);
  hipLaunchKernelGGL(concat_kernel, dim3(4096), dim3(256), 0, stream,
                     Wskew, Wk, Wv, Wq, Wbeta, Wo, Wh, Wl, WoT);
  hipLaunchKernelGGL(gemm_proj_kernel, dim3(128,7), dim3(256), 0, stream,
                     xh, xl, Wh, Wl, proj, bbeta);
  hipLaunchKernelGGL(expm_scan_kernel, dim3(4096), dim3(64), 0, stream, proj, ORbf, Pfin);
  hipLaunchKernelGGL(chunkscan_kernel, dim3(64), dim3(64), 0, stream, Pfin, Rbase);
  hipLaunchKernelGGL(rotate_kvq_kernel, dim3(1024), dim3(256), 0, stream, ORbf, Rbase, proj);
  hipLaunchKernelGGL(scan_pass1_kernel, dim3(512), dim3(256), 0, stream, proj, Mbuf, wbuf);
  hipLaunchKernelGGL(scan_mid_kernel, dim3(64), dim3(512), 0, stream, Mbuf, wbuf, dstart);
  hipLaunchKernelGGL(scan_pass2_kernel, dim3(512), dim3(256), 0, stream, proj, dstart, oo);
  hipLaunchKernelGGL(rotout_kernel, dim3(1024), dim3(256), 0, stream, ORbf, Rbase, oo, obf);
  hipLaunchKernelGGL(gemm_out_kernel, dim3(128,8), dim3(256), 0, stream,
                     obf, WoT, (float*)d_out);
}